// Round 2
// baseline (484.402 us; speedup 1.0000x reference)
//
#include <hip/hip_runtime.h>
#include <hip/hip_bf16.h>
#include <math.h>

#define Bn 8
#define Cn 96
#define Hn 128
#define Wn 128
#define PLANE (Hn*Wn)          // 16384
#define NIMG (Bn*Cn*PLANE)     // 12582912
#define EPSV 1e-5f
#define TAPN 48                // dense tap window: offsets [-23, 24]

// ---------------------------------------------------------------------------
// K0: build merged per-(channel,direction) sparse integer tap lists.
// t = m + l = 2x + sum of 4 interpolated 5-tap convs; each conv tap at
// fractional offset off*r splits into integer taps floor(off*r) (w*(1-frac))
// and floor(off*r)+1 (w*frac). Merge both convs per direction per channel.
// ---------------------------------------------------------------------------
__global__ void k0_taps(
    const float* __restrict__ rm_p, const float* __restrict__ whm, const float* __restrict__ wwm,
    const float* __restrict__ rl_p, const float* __restrict__ whl, const float* __restrict__ wwl,
    int* __restrict__ cnt, int* __restrict__ offs, float* __restrict__ wts)
{
    int t = threadIdx.x;              // 0..191
    if (t >= Cn * 2) return;
    int c = t >> 1, dir = t & 1;
    const float* tap_m = dir ? (wwm + c * 5) : (whm + c * 5);
    const float* tap_l = dir ? (wwl + c * 5) : (whl + c * 5);
    float rm = fmaxf(rm_p[0], 1.f), rl = fmaxf(rl_p[0], 1.f);
    float dense[TAPN];
    for (int k = 0; k < TAPN; ++k) dense[k] = 0.f;
    for (int pass = 0; pass < 2; ++pass) {
        float r = pass ? rl : rm;
        const float* tp = pass ? tap_l : tap_m;
        for (int i = 0; i < 5; ++i) {
            float s = (float)(i - 2) * r;
            float f = floorf(s);
            float fr = s - f;
            int fi = (int)f + 23;
            if (fi >= 0 && fi < TAPN)     dense[fi]     += tp[i] * (1.f - fr);
            if (fi + 1 >= 0 && fi + 1 < TAPN) dense[fi + 1] += tp[i] * fr;
        }
    }
    int n = 0;
    for (int k = 0; k < TAPN; ++k) {
        if (dense[k] != 0.f) {
            offs[t * TAPN + n] = k - 23;
            wts[t * TAPN + n] = dense[k];
            ++n;
        }
    }
    cnt[t] = n;
}

// ---------------------------------------------------------------------------
// K1: t = 2x + sparse-FIR(H) + sparse-FIR(W), one (b,c) plane per block,
// plane staged in LDS (64 KB). All gathers are conflict-free ds_read_b32.
// ---------------------------------------------------------------------------
__global__ __launch_bounds__(256) void k1_axial(
    const float* __restrict__ x,
    const int* __restrict__ cnt, const int* __restrict__ offs, const float* __restrict__ wts,
    float* __restrict__ t_out)
{
    __shared__ float pl[PLANE];            // 64 KB
    __shared__ int   soff[2 * TAPN];
    __shared__ float swt[2 * TAPN];
    __shared__ int   scnt[2];
    int bc = blockIdx.x;                   // 768
    int c  = bc % Cn;
    int tid = threadIdx.x;

    const float4* src = (const float4*)(x + ((long)bc << 14));
    float4* pl4 = (float4*)pl;
#pragma unroll
    for (int e = 0; e < 16; ++e) pl4[e * 256 + tid] = src[e * 256 + tid];
    if (tid < 2) scnt[tid] = cnt[c * 2 + tid];
    if (tid < 2 * TAPN) {
        int dir = tid / TAPN, j = tid - dir * TAPN;
        soff[tid] = offs[(c * 2 + dir) * TAPN + j];
        swt[tid]  = wts[(c * 2 + dir) * TAPN + j];
    }
    __syncthreads();

    int cH = scnt[0], cW = scnt[1];
    float* t_o = t_out + ((long)bc << 14);
    for (int e = 0; e < 64; ++e) {
        int p = e * 256 + tid;
        int w = p & 127, h = p >> 7;       // h is wave-uniform
        float acc = 2.f * pl[p];
        for (int j = 0; j < cH; ++j) {
            int y = h + soff[j];
            if (y >= 0 && y < Hn)          // wave-uniform branch
                acc += swt[j] * pl[(y << 7) + w];
        }
        for (int j = 0; j < cW; ++j) {
            int xw = w + soff[TAPN + j];
            int xc = min(max(xw, 0), Wn - 1);
            float v = pl[(h << 7) + xc];
            acc += (xw == xc ? swt[TAPN + j] : 0.f) * v;
        }
        t_o[p] = acc;
    }
}

// ---------------------------------------------------------------------------
// K2: out_pre = prelu( BN(w_fuse @ t) + BN(x + edges), act_a )
// Block: 64 consecutive pixels (one half-row, single h) x all 96 channels.
// ---------------------------------------------------------------------------
__global__ __launch_bounds__(256) void k2_pw(
    const float* __restrict__ t_g, const float* __restrict__ x,
    const float* __restrict__ w_fuse,
    const float* __restrict__ bg, const float* __restrict__ bb,
    const float* __restrict__ bm, const float* __restrict__ bv,
    const float* __restrict__ dwh, const float* __restrict__ dww,
    const float* __restrict__ dg, const float* __restrict__ db_,
    const float* __restrict__ dm, const float* __restrict__ dv,
    const float* __restrict__ act_a,
    float* __restrict__ out_pre)
{
    __shared__ float tl[Cn * 64];        // 24 KB
    __shared__ float wl[Cn * 97];        // 37.2 KB (pad 96->97 kills bank conflicts)
    int tid = threadIdx.x;
    int blk = blockIdx.x;                // 2048
    int b  = blk >> 8;
    int p0 = (blk & 255) * 64;
    int h  = p0 >> 7;
    int w0 = p0 & 127;
    long base_b = (long)b * Cn * PLANE;

    for (int e = tid; e < Cn * Cn; e += 256) {
        int o = e / Cn;
        int c = e - o * Cn;
        wl[o * 97 + c] = w_fuse[e];
    }
    for (int e = tid; e < Cn * 64; e += 256) {
        int c = e >> 6;
        int p = e & 63;
        tl[c * 64 + p] = t_g[base_b + c * PLANE + p0 + p];
    }
    __syncthreads();

    int pix4 = tid & 15;     // 4 consecutive pixels: wc..wc+3
    int og   = tid >> 4;     // 16 groups x 6 output channels
    float acc[6][4];
#pragma unroll
    for (int j = 0; j < 6; ++j)
#pragma unroll
        for (int k = 0; k < 4; ++k) acc[j][k] = 0.f;

    for (int c = 0; c < Cn; ++c) {
        float4 tv = *(const float4*)&tl[c * 64 + pix4 * 4];
#pragma unroll
        for (int j = 0; j < 6; ++j) {
            float wv = wl[(og * 6 + j) * 97 + c];
            acc[j][0] += wv * tv.x;
            acc[j][1] += wv * tv.y;
            acc[j][2] += wv * tv.z;
            acc[j][3] += wv * tv.w;
        }
    }

    int wc = w0 + pix4 * 4;
#pragma unroll
    for (int j = 0; j < 6; ++j) {
        int o = og * 6 + j;
        const float* xp = x + base_b + (long)o * PLANE + (h << 7) + wc;
        float4 cx = *(const float4*)xp;
        float4 up = (h > 0)       ? *(const float4*)(xp - Wn) : make_float4(0, 0, 0, 0);
        float4 dn = (h < Hn - 1)  ? *(const float4*)(xp + Wn) : make_float4(0, 0, 0, 0);
        float lf = (wc > 0)       ? xp[-1] : 0.f;
        float rt = (wc + 4 < Wn)  ? xp[4]  : 0.f;
        float cxa[4] = {cx.x, cx.y, cx.z, cx.w};
        float upa[4] = {up.x, up.y, up.z, up.w};
        float dna[4] = {dn.x, dn.y, dn.z, dn.w};
        float lva[4] = {lf, cx.x, cx.y, cx.z};
        float rva[4] = {cx.y, cx.z, cx.w, rt};
        float wh0 = dwh[o * 3], wh1 = dwh[o * 3 + 1], wh2 = dwh[o * 3 + 2];
        float ww0 = dww[o * 3], ww1 = dww[o * 3 + 1], ww2 = dww[o * 3 + 2];
        float dsc = dg[o] * rsqrtf(dv[o] + EPSV);
        float dof = db_[o] - dm[o] * dsc;
        float fsc = bg[o] * rsqrtf(bv[o] + EPSV);
        float fof = bb[o] - bm[o] * fsc;
        float aa  = act_a[o];
        float4 res;
        float r4[4];
#pragma unroll
        for (int k = 0; k < 4; ++k) {
            float edges = wh0 * upa[k] + wh1 * cxa[k] + wh2 * dna[k]
                        + ww0 * lva[k] + ww1 * cxa[k] + ww2 * rva[k];
            float anch = (cxa[k] + edges) * dsc + dof;
            float fused = acc[j][k] * fsc + fof;
            float v = fused + anch;
            r4[k] = (v >= 0.f) ? v : aa * v;
        }
        res.x = r4[0]; res.y = r4[1]; res.z = r4[2]; res.w = r4[3];
        *(float4*)&out_pre[base_b + (long)o * PLANE + (h << 7) + wc] = res;
    }
}

// ---------------------------------------------------------------------------
// K3: per-(b,c) plane: row means (over w) -> xh, column means (over h) -> xw
// float4 loads; 256 threads = 32 colgroups x 8 rowgroups.
// ---------------------------------------------------------------------------
__global__ __launch_bounds__(256) void k3_means(
    const float* __restrict__ op, float* __restrict__ xh, float* __restrict__ xw)
{
    int bc = blockIdx.x;                 // 768
    const float4* pl = (const float4*)(op + ((long)bc << 14));
    int tid = threadIdx.x;
    int wq = tid & 31;                   // covers w = wq*4 .. wq*4+3
    int hg = tid >> 5;                   // 0..7
    __shared__ float cpart[8][Wn + 4];
    __shared__ float rpart[Hn];
    float4 csum = make_float4(0, 0, 0, 0);
#pragma unroll
    for (int k = 0; k < 16; ++k) {
        int h = hg * 16 + k;
        float4 v = pl[h * 32 + wq];
        csum.x += v.x; csum.y += v.y; csum.z += v.z; csum.w += v.w;
        float rs = v.x + v.y + v.z + v.w;
#pragma unroll
        for (int off = 16; off; off >>= 1) rs += __shfl_down(rs, off, 32);
        if (wq == 0) rpart[h] = rs * (1.f / Wn);
    }
    cpart[hg][wq * 4 + 0] = csum.x;
    cpart[hg][wq * 4 + 1] = csum.y;
    cpart[hg][wq * 4 + 2] = csum.z;
    cpart[hg][wq * 4 + 3] = csum.w;
    __syncthreads();
    if (tid < 128) {
        float s = 0.f;
#pragma unroll
        for (int g = 0; g < 8; ++g) s += cpart[g][tid];
        xw[bc * Wn + tid] = s * (1.f / Hn);
        xh[bc * Hn + tid] = rpart[tid];
    }
}

// ---------------------------------------------------------------------------
// K4: coord-attention MLP: y2 = prelu(BN(ca_w1 @ [xh;xw])); a = sigmoid(W @ y2)
// ---------------------------------------------------------------------------
__global__ __launch_bounds__(256) void k4_att(
    const float* __restrict__ xh, const float* __restrict__ xw,
    const float* __restrict__ w1,
    const float* __restrict__ g, const float* __restrict__ bb,
    const float* __restrict__ m, const float* __restrict__ v,
    const float* __restrict__ aa,
    const float* __restrict__ cwh, const float* __restrict__ cww,
    float* __restrict__ a_h, float* __restrict__ a_w)
{
    int b = blockIdx.x;      // 8
    int p = threadIdx.x;     // 256 = H + W positions
    __shared__ float w1s[8 * Cn];
    __shared__ float whs[Cn * 8];
    __shared__ float wws[Cn * 8];
    for (int e = p; e < 8 * Cn; e += 256) { w1s[e] = w1[e]; whs[e] = cwh[e]; wws[e] = cww[e]; }
    __syncthreads();

    float acc[8];
#pragma unroll
    for (int i = 0; i < 8; ++i) acc[i] = 0.f;
    for (int c = 0; c < Cn; ++c) {
        float yv = (p < Hn) ? xh[(b * Cn + c) * Hn + p] : xw[(b * Cn + c) * Wn + (p - Hn)];
#pragma unroll
        for (int mip = 0; mip < 8; ++mip) acc[mip] += w1s[mip * Cn + c] * yv;
    }
    float y2[8];
#pragma unroll
    for (int mip = 0; mip < 8; ++mip) {
        float sc = g[mip] * rsqrtf(v[mip] + EPSV);
        float t = (acc[mip] - m[mip]) * sc + bb[mip];
        y2[mip] = (t >= 0.f) ? t : aa[mip] * t;
    }
    const float* wsel = (p < Hn) ? whs : wws;
    float* osel = (p < Hn) ? a_h : a_w;
    int pp = (p < Hn) ? p : p - Hn;
    for (int c = 0; c < Cn; ++c) {
        float s = 0.f;
#pragma unroll
        for (int mip = 0; mip < 8; ++mip) s += wsel[c * 8 + mip] * y2[mip];
        osel[(b * Cn + c) * Hn + pp] = 1.f / (1.f + expf(-s));
    }
}

// ---------------------------------------------------------------------------
// K5: out = out_pre * a_h[b,c,h] * a_w[b,c,w]   (float4)
// ---------------------------------------------------------------------------
__global__ __launch_bounds__(256) void k5_final(
    const float* __restrict__ op, const float* __restrict__ a_h,
    const float* __restrict__ a_w, float* __restrict__ out)
{
    int idx = blockIdx.x * 256 + threadIdx.x;
    int e = idx * 4;
    if (e >= NIMG) return;
    int w = e & 127;
    int h = (e >> 7) & 127;
    int bc = e >> 14;
    float4 vv = *(const float4*)(op + e);
    float ah = a_h[bc * Hn + h];
    float4 aw = *(const float4*)(a_w + bc * Wn + w);
    float4 r;
    r.x = vv.x * ah * aw.x;
    r.y = vv.y * ah * aw.y;
    r.z = vv.z * ah * aw.z;
    r.w = vv.w * ah * aw.w;
    *(float4*)(out + e) = r;
}

// ---------------------------------------------------------------------------
extern "C" void kernel_launch(void* const* d_in, const int* in_sizes, int n_in,
                              void* d_out, int out_size, void* d_ws, size_t ws_size,
                              hipStream_t stream)
{
    const float* x     = (const float*)d_in[0];
    const float* r_m   = (const float*)d_in[1];
    const float* wh_m  = (const float*)d_in[2];
    const float* ww_m  = (const float*)d_in[3];
    const float* r_l   = (const float*)d_in[4];
    const float* wh_l  = (const float*)d_in[5];
    const float* ww_l  = (const float*)d_in[6];
    const float* wfuse = (const float*)d_in[7];
    const float* bnf_g = (const float*)d_in[8];
    const float* bnf_b = (const float*)d_in[9];
    const float* bnf_m = (const float*)d_in[10];
    const float* bnf_v = (const float*)d_in[11];
    const float* dg_wh = (const float*)d_in[12];
    const float* dg_ww = (const float*)d_in[13];
    const float* dg_g  = (const float*)d_in[14];
    const float* dg_b  = (const float*)d_in[15];
    const float* dg_m  = (const float*)d_in[16];
    const float* dg_v  = (const float*)d_in[17];
    const float* act_a = (const float*)d_in[18];
    const float* ca_w1 = (const float*)d_in[19];
    const float* ca_g  = (const float*)d_in[20];
    const float* ca_b  = (const float*)d_in[21];
    const float* ca_m  = (const float*)d_in[22];
    const float* ca_v  = (const float*)d_in[23];
    const float* ca_a  = (const float*)d_in[24];
    const float* ca_wh = (const float*)d_in[25];
    const float* ca_ww = (const float*)d_in[26];

    float* ws      = (float*)d_ws;
    float* t_buf   = ws;                     // NIMG
    float* out_pre = ws + (size_t)NIMG;      // NIMG
    float* xh      = out_pre + (size_t)NIMG; // B*C*H = 98304
    float* xw      = xh + Bn * Cn * Hn;
    float* a_h     = xw + Bn * Cn * Wn;
    float* a_w     = a_h + Bn * Cn * Hn;
    float* wts     = a_w + Bn * Cn * Wn;     // 192*TAPN floats
    int*   cnt     = (int*)(wts + 2 * Cn * TAPN);  // 192 ints
    int*   offs    = cnt + 2 * Cn;                 // 192*TAPN ints

    float* out = (float*)d_out;

    hipLaunchKernelGGL(k0_taps, dim3(1), dim3(192), 0, stream,
                       r_m, wh_m, ww_m, r_l, wh_l, ww_l, cnt, offs, wts);
    hipLaunchKernelGGL(k1_axial, dim3(Bn * Cn), dim3(256), 0, stream,
                       x, cnt, offs, wts, t_buf);
    hipLaunchKernelGGL(k2_pw, dim3(Bn * PLANE / 64), dim3(256), 0, stream,
                       t_buf, x, wfuse, bnf_g, bnf_b, bnf_m, bnf_v,
                       dg_wh, dg_ww, dg_g, dg_b, dg_m, dg_v, act_a, out_pre);
    hipLaunchKernelGGL(k3_means, dim3(Bn * Cn), dim3(256), 0, stream,
                       out_pre, xh, xw);
    hipLaunchKernelGGL(k4_att, dim3(Bn), dim3(256), 0, stream,
                       xh, xw, ca_w1, ca_g, ca_b, ca_m, ca_v, ca_a, ca_wh, ca_ww,
                       a_h, a_w);
    hipLaunchKernelGGL(k5_final, dim3(NIMG / 1024), dim3(256), 0, stream,
                       out_pre, a_h, a_w, out);
}

// Round 3
// 348.908 us; speedup vs baseline: 1.3883x; 1.3883x over previous
//
#include <hip/hip_runtime.h>
#include <hip/hip_bf16.h>
#include <math.h>

#define Bn 8
#define Cn 96
#define Hn 128
#define Wn 128
#define PLANE (Hn*Wn)          // 16384
#define NIMG (Bn*Cn*PLANE)     // 12582912
#define EPSV 1e-5f
#define TAPN 48                // tap storage capacity per (c,dir)
#define TAPF 8                 // fast-path fixed tap count per direction

// ---------------------------------------------------------------------------
// K0: build merged per-(channel,direction) sparse integer tap lists,
// zero-padded to TAPN so the fast path can blindly read TAPF entries.
// ---------------------------------------------------------------------------
__global__ void k0_taps(
    const float* __restrict__ rm_p, const float* __restrict__ whm, const float* __restrict__ wwm,
    const float* __restrict__ rl_p, const float* __restrict__ whl, const float* __restrict__ wwl,
    int* __restrict__ cnt, int* __restrict__ offs, float* __restrict__ wts)
{
    int t = threadIdx.x;              // 0..191
    if (t >= Cn * 2) return;
    int c = t >> 1, dir = t & 1;
    // zero-fill (ws is poisoned 0xAA before every call)
    for (int k = 0; k < TAPN; ++k) { offs[t * TAPN + k] = 0; wts[t * TAPN + k] = 0.f; }
    const float* tap_m = dir ? (wwm + c * 5) : (whm + c * 5);
    const float* tap_l = dir ? (wwl + c * 5) : (whl + c * 5);
    float rm = fmaxf(rm_p[0], 1.f), rl = fmaxf(rl_p[0], 1.f);
    float dense[TAPN];
    for (int k = 0; k < TAPN; ++k) dense[k] = 0.f;
    for (int pass = 0; pass < 2; ++pass) {
        float r = pass ? rl : rm;
        const float* tp = pass ? tap_l : tap_m;
        for (int i = 0; i < 5; ++i) {
            float s = (float)(i - 2) * r;
            float f = floorf(s);
            float fr = s - f;
            int fi = (int)f + 23;
            if (fi >= 0 && fi < TAPN)         dense[fi]     += tp[i] * (1.f - fr);
            if (fi + 1 >= 0 && fi + 1 < TAPN) dense[fi + 1] += tp[i] * fr;
        }
    }
    int n = 0;
    for (int k = 0; k < TAPN; ++k) {
        if (dense[k] != 0.f) {
            offs[t * TAPN + n] = k - 23;
            wts[t * TAPN + n] = dense[k];
            ++n;
        }
    }
    cnt[t] = n;
}

// ---------------------------------------------------------------------------
// K1: t = 2x + sparse-FIR(H) + sparse-FIR(W).
// Block = one (b,c) plane slice of 8 rows. Thread owns 4 stride-32 pixels of
// one row -> all LDS accesses conflict-free, all global b32 coalesced.
// W-taps from LDS (rows staged, zero-padded +-16 cols); H-taps from global
// (L1/L2 serves neighbor-row reuse). Fast path: TAPF taps fully unrolled.
// ---------------------------------------------------------------------------
__global__ __launch_bounds__(256) void k1_axial(
    const float* __restrict__ x,
    const int* __restrict__ cnt, const int* __restrict__ offs, const float* __restrict__ wts,
    float* __restrict__ t_out)
{
    __shared__ float pl[8][160];        // 16-col zero pad each side, 5 KB
    __shared__ int   soff[2 * TAPF];
    __shared__ float swt[2 * TAPF];
    __shared__ int   scnt[2];

    int blk = blockIdx.x;               // 768*16
    int bc  = blk >> 4;
    int hg  = blk & 15;
    int c   = bc % Cn;
    int tid = threadIdx.x;
    int m   = tid & 31;                 // column base
    int row = tid >> 5;                 // 0..7
    int h   = hg * 8 + row;

    if (tid < 2) scnt[tid] = cnt[c * 2 + tid];
    if (tid < 2 * TAPF) {
        int dir = tid >> 3, j = tid & (TAPF - 1);
        soff[tid] = offs[(c * 2 + dir) * TAPN + j];
        swt[tid]  = wts[(c * 2 + dir) * TAPN + j];
    }
    // zero pads: 8 rows x 32 pad floats == 256 threads
    {
        int pr = tid >> 5, pp = tid & 31;
        pl[pr][pp < 16 ? pp : 128 + pp] = 0.f;   // 0..15 and 144..159
    }
    const float* plane = x + ((long)bc << 14);
    const float* rowp  = plane + (h << 7);
    float v0 = rowp[m], v1 = rowp[m + 32], v2 = rowp[m + 64], v3 = rowp[m + 96];
    pl[row][16 + m]      = v0;
    pl[row][16 + m + 32] = v1;
    pl[row][16 + m + 64] = v2;
    pl[row][16 + m + 96] = v3;
    __syncthreads();

    int cH = scnt[0], cW = scnt[1];
    float a0 = 2.f * v0, a1 = 2.f * v1, a2 = 2.f * v2, a3 = 2.f * v3;

    bool fast = (cH <= TAPF) && (cW <= TAPF);
#pragma unroll
    for (int j = 0; j < TAPF; ++j)
        fast = fast && (soff[TAPF + j] >= -16) && (soff[TAPF + j] <= 16);

    if (fast) {
#pragma unroll
        for (int j = 0; j < TAPF; ++j) {       // H taps (global)
            int y = h + soff[j];
            float wt = (y >= 0 && y < Hn) ? swt[j] : 0.f;
            y = min(max(y, 0), Hn - 1);
            const float* rp = plane + (y << 7);
            a0 += wt * rp[m];
            a1 += wt * rp[m + 32];
            a2 += wt * rp[m + 64];
            a3 += wt * rp[m + 96];
        }
#pragma unroll
        for (int j = 0; j < TAPF; ++j) {       // W taps (LDS, padded)
            int o = soff[TAPF + j];
            float wt = swt[TAPF + j];
            const float* rp = &pl[row][16 + o];
            a0 += wt * rp[m];
            a1 += wt * rp[m + 32];
            a2 += wt * rp[m + 64];
            a3 += wt * rp[m + 96];
        }
    } else {
        // generic fallback (arbitrary r): global gathers, runtime counts
        const int*   goH = offs + (c * 2 + 0) * TAPN;
        const float* gwH = wts  + (c * 2 + 0) * TAPN;
        const int*   goW = offs + (c * 2 + 1) * TAPN;
        const float* gwW = wts  + (c * 2 + 1) * TAPN;
        for (int j = 0; j < cH; ++j) {
            int y = h + goH[j];
            if (y >= 0 && y < Hn) {
                float wt = gwH[j];
                const float* rp = plane + (y << 7);
                a0 += wt * rp[m];
                a1 += wt * rp[m + 32];
                a2 += wt * rp[m + 64];
                a3 += wt * rp[m + 96];
            }
        }
        for (int j = 0; j < cW; ++j) {
            int o = goW[j];
            float wt = gwW[j];
            const float* rp = plane + (h << 7);
#pragma unroll
            for (int q = 0; q < 4; ++q) {
                int xw = m + 32 * q + o;
                float v = (xw >= 0 && xw < Wn) ? rp[xw] : 0.f;
                float* ap = (q == 0) ? &a0 : (q == 1) ? &a1 : (q == 2) ? &a2 : &a3;
                *ap += wt * v;
            }
        }
    }

    float* t_o = t_out + ((long)bc << 14) + (h << 7);
    t_o[m]      = a0;
    t_o[m + 32] = a1;
    t_o[m + 64] = a2;
    t_o[m + 96] = a3;
}

// ---------------------------------------------------------------------------
// K2: out_pre = prelu( BN(w_fuse @ t) + BN(x + edges), act_a )
// Block: 64 consecutive pixels (one half-row, single h) x all 96 channels.
// Weights read as float4 along c (stride padded to 100).
// ---------------------------------------------------------------------------
__global__ __launch_bounds__(256) void k2_pw(
    const float* __restrict__ t_g, const float* __restrict__ x,
    const float* __restrict__ w_fuse,
    const float* __restrict__ bg, const float* __restrict__ bb,
    const float* __restrict__ bm, const float* __restrict__ bv,
    const float* __restrict__ dwh, const float* __restrict__ dww,
    const float* __restrict__ dg, const float* __restrict__ db_,
    const float* __restrict__ dm, const float* __restrict__ dv,
    const float* __restrict__ act_a,
    float* __restrict__ out_pre)
{
    __shared__ float tl[Cn * 64];         // 24 KB
    __shared__ float wl[Cn * 100];        // 38.4 KB, float4-readable rows
    int tid = threadIdx.x;
    int blk = blockIdx.x;                 // 2048
    int b  = blk >> 8;
    int p0 = (blk & 255) * 64;
    int h  = p0 >> 7;
    int w0 = p0 & 127;
    long base_b = (long)b * Cn * PLANE;

    for (int e = tid; e < Cn * Cn; e += 256) {
        int o = e / Cn;
        int c = e - o * Cn;
        wl[o * 100 + c] = w_fuse[e];
    }
    for (int e = tid; e < Cn * 64; e += 256) {
        int c = e >> 6;
        int p = e & 63;
        tl[c * 64 + p] = t_g[base_b + c * PLANE + p0 + p];
    }
    __syncthreads();

    int pix4 = tid & 15;     // 4 consecutive pixels
    int og   = tid >> 4;     // 16 groups x 6 output channels
    float acc[6][4];
#pragma unroll
    for (int j = 0; j < 6; ++j)
#pragma unroll
        for (int k = 0; k < 4; ++k) acc[j][k] = 0.f;

    for (int c = 0; c < Cn; c += 4) {
        float4 tv[4];
#pragma unroll
        for (int q = 0; q < 4; ++q) tv[q] = *(const float4*)&tl[(c + q) * 64 + pix4 * 4];
#pragma unroll
        for (int j = 0; j < 6; ++j) {
            float4 wv = *(const float4*)&wl[(og * 6 + j) * 100 + c];
            acc[j][0] += wv.x * tv[0].x + wv.y * tv[1].x + wv.z * tv[2].x + wv.w * tv[3].x;
            acc[j][1] += wv.x * tv[0].y + wv.y * tv[1].y + wv.z * tv[2].y + wv.w * tv[3].y;
            acc[j][2] += wv.x * tv[0].z + wv.y * tv[1].z + wv.z * tv[2].z + wv.w * tv[3].z;
            acc[j][3] += wv.x * tv[0].w + wv.y * tv[1].w + wv.z * tv[2].w + wv.w * tv[3].w;
        }
    }

    int wc = w0 + pix4 * 4;
#pragma unroll
    for (int j = 0; j < 6; ++j) {
        int o = og * 6 + j;
        const float* xp = x + base_b + (long)o * PLANE + (h << 7) + wc;
        float4 cx = *(const float4*)xp;
        float4 up = (h > 0)       ? *(const float4*)(xp - Wn) : make_float4(0, 0, 0, 0);
        float4 dn = (h < Hn - 1)  ? *(const float4*)(xp + Wn) : make_float4(0, 0, 0, 0);
        float lf = (wc > 0)       ? xp[-1] : 0.f;
        float rt = (wc + 4 < Wn)  ? xp[4]  : 0.f;
        float cxa[4] = {cx.x, cx.y, cx.z, cx.w};
        float upa[4] = {up.x, up.y, up.z, up.w};
        float dna[4] = {dn.x, dn.y, dn.z, dn.w};
        float lva[4] = {lf, cx.x, cx.y, cx.z};
        float rva[4] = {cx.y, cx.z, cx.w, rt};
        float wh0 = dwh[o * 3], wh1 = dwh[o * 3 + 1], wh2 = dwh[o * 3 + 2];
        float ww0 = dww[o * 3], ww1 = dww[o * 3 + 1], ww2 = dww[o * 3 + 2];
        float dsc = dg[o] * rsqrtf(dv[o] + EPSV);
        float dof = db_[o] - dm[o] * dsc;
        float fsc = bg[o] * rsqrtf(bv[o] + EPSV);
        float fof = bb[o] - bm[o] * fsc;
        float aa  = act_a[o];
        float4 res;
        float r4[4];
#pragma unroll
        for (int k = 0; k < 4; ++k) {
            float edges = wh0 * upa[k] + wh1 * cxa[k] + wh2 * dna[k]
                        + ww0 * lva[k] + ww1 * cxa[k] + ww2 * rva[k];
            float anch = (cxa[k] + edges) * dsc + dof;
            float fused = acc[j][k] * fsc + fof;
            float v = fused + anch;
            r4[k] = (v >= 0.f) ? v : aa * v;
        }
        res.x = r4[0]; res.y = r4[1]; res.z = r4[2]; res.w = r4[3];
        *(float4*)&out_pre[base_b + (long)o * PLANE + (h << 7) + wc] = res;
    }
}

// ---------------------------------------------------------------------------
// K3: per-(b,c) plane: row means (over w) -> xh, column means (over h) -> xw
// ---------------------------------------------------------------------------
__global__ __launch_bounds__(256) void k3_means(
    const float* __restrict__ op, float* __restrict__ xh, float* __restrict__ xw)
{
    int bc = blockIdx.x;                 // 768
    const float4* pl = (const float4*)(op + ((long)bc << 14));
    int tid = threadIdx.x;
    int wq = tid & 31;
    int hg = tid >> 5;
    __shared__ float cpart[8][Wn + 4];
    __shared__ float rpart[Hn];
    float4 csum = make_float4(0, 0, 0, 0);
#pragma unroll
    for (int k = 0; k < 16; ++k) {
        int h = hg * 16 + k;
        float4 v = pl[h * 32 + wq];
        csum.x += v.x; csum.y += v.y; csum.z += v.z; csum.w += v.w;
        float rs = v.x + v.y + v.z + v.w;
#pragma unroll
        for (int off = 16; off; off >>= 1) rs += __shfl_down(rs, off, 32);
        if (wq == 0) rpart[h] = rs * (1.f / Wn);
    }
    cpart[hg][wq * 4 + 0] = csum.x;
    cpart[hg][wq * 4 + 1] = csum.y;
    cpart[hg][wq * 4 + 2] = csum.z;
    cpart[hg][wq * 4 + 3] = csum.w;
    __syncthreads();
    if (tid < 128) {
        float s = 0.f;
#pragma unroll
        for (int g = 0; g < 8; ++g) s += cpart[g][tid];
        xw[bc * Wn + tid] = s * (1.f / Hn);
        xh[bc * Hn + tid] = rpart[tid];
    }
}

// ---------------------------------------------------------------------------
// K4: coord-attention MLP
// ---------------------------------------------------------------------------
__global__ __launch_bounds__(256) void k4_att(
    const float* __restrict__ xh, const float* __restrict__ xw,
    const float* __restrict__ w1,
    const float* __restrict__ g, const float* __restrict__ bb,
    const float* __restrict__ m, const float* __restrict__ v,
    const float* __restrict__ aa,
    const float* __restrict__ cwh, const float* __restrict__ cww,
    float* __restrict__ a_h, float* __restrict__ a_w)
{
    int b = blockIdx.x;      // 8
    int p = threadIdx.x;     // 256 = H + W positions
    __shared__ float w1s[8 * Cn];
    __shared__ float whs[Cn * 8];
    __shared__ float wws[Cn * 8];
    for (int e = p; e < 8 * Cn; e += 256) { w1s[e] = w1[e]; whs[e] = cwh[e]; wws[e] = cww[e]; }
    __syncthreads();

    float acc[8];
#pragma unroll
    for (int i = 0; i < 8; ++i) acc[i] = 0.f;
    for (int c = 0; c < Cn; ++c) {
        float yv = (p < Hn) ? xh[(b * Cn + c) * Hn + p] : xw[(b * Cn + c) * Wn + (p - Hn)];
#pragma unroll
        for (int mip = 0; mip < 8; ++mip) acc[mip] += w1s[mip * Cn + c] * yv;
    }
    float y2[8];
#pragma unroll
    for (int mip = 0; mip < 8; ++mip) {
        float sc = g[mip] * rsqrtf(v[mip] + EPSV);
        float t = (acc[mip] - m[mip]) * sc + bb[mip];
        y2[mip] = (t >= 0.f) ? t : aa[mip] * t;
    }
    const float* wsel = (p < Hn) ? whs : wws;
    float* osel = (p < Hn) ? a_h : a_w;
    int pp = (p < Hn) ? p : p - Hn;
    for (int c = 0; c < Cn; ++c) {
        float s = 0.f;
#pragma unroll
        for (int mip = 0; mip < 8; ++mip) s += wsel[c * 8 + mip] * y2[mip];
        osel[(b * Cn + c) * Hn + pp] = 1.f / (1.f + expf(-s));
    }
}

// ---------------------------------------------------------------------------
// K5: out = out_pre * a_h[b,c,h] * a_w[b,c,w]   (float4)
// ---------------------------------------------------------------------------
__global__ __launch_bounds__(256) void k5_final(
    const float* __restrict__ op, const float* __restrict__ a_h,
    const float* __restrict__ a_w, float* __restrict__ out)
{
    int idx = blockIdx.x * 256 + threadIdx.x;
    int e = idx * 4;
    if (e >= NIMG) return;
    int w = e & 127;
    int h = (e >> 7) & 127;
    int bc = e >> 14;
    float4 vv = *(const float4*)(op + e);
    float ah = a_h[bc * Hn + h];
    float4 aw = *(const float4*)(a_w + bc * Wn + w);
    float4 r;
    r.x = vv.x * ah * aw.x;
    r.y = vv.y * ah * aw.y;
    r.z = vv.z * ah * aw.z;
    r.w = vv.w * ah * aw.w;
    *(float4*)(out + e) = r;
}

// ---------------------------------------------------------------------------
extern "C" void kernel_launch(void* const* d_in, const int* in_sizes, int n_in,
                              void* d_out, int out_size, void* d_ws, size_t ws_size,
                              hipStream_t stream)
{
    const float* x     = (const float*)d_in[0];
    const float* r_m   = (const float*)d_in[1];
    const float* wh_m  = (const float*)d_in[2];
    const float* ww_m  = (const float*)d_in[3];
    const float* r_l   = (const float*)d_in[4];
    const float* wh_l  = (const float*)d_in[5];
    const float* ww_l  = (const float*)d_in[6];
    const float* wfuse = (const float*)d_in[7];
    const float* bnf_g = (const float*)d_in[8];
    const float* bnf_b = (const float*)d_in[9];
    const float* bnf_m = (const float*)d_in[10];
    const float* bnf_v = (const float*)d_in[11];
    const float* dg_wh = (const float*)d_in[12];
    const float* dg_ww = (const float*)d_in[13];
    const float* dg_g  = (const float*)d_in[14];
    const float* dg_b  = (const float*)d_in[15];
    const float* dg_m  = (const float*)d_in[16];
    const float* dg_v  = (const float*)d_in[17];
    const float* act_a = (const float*)d_in[18];
    const float* ca_w1 = (const float*)d_in[19];
    const float* ca_g  = (const float*)d_in[20];
    const float* ca_b  = (const float*)d_in[21];
    const float* ca_m  = (const float*)d_in[22];
    const float* ca_v  = (const float*)d_in[23];
    const float* ca_a  = (const float*)d_in[24];
    const float* ca_wh = (const float*)d_in[25];
    const float* ca_ww = (const float*)d_in[26];

    float* ws      = (float*)d_ws;
    float* t_buf   = ws;                     // NIMG
    float* out_pre = ws + (size_t)NIMG;      // NIMG
    float* xh      = out_pre + (size_t)NIMG; // B*C*H
    float* xw      = xh + Bn * Cn * Hn;
    float* a_h     = xw + Bn * Cn * Wn;
    float* a_w     = a_h + Bn * Cn * Hn;
    float* wts     = a_w + Bn * Cn * Wn;     // 192*TAPN floats
    int*   cnt     = (int*)(wts + 2 * Cn * TAPN);  // 192 ints
    int*   offs    = cnt + 2 * Cn;                 // 192*TAPN ints

    float* out = (float*)d_out;

    hipLaunchKernelGGL(k0_taps, dim3(1), dim3(192), 0, stream,
                       r_m, wh_m, ww_m, r_l, wh_l, ww_l, cnt, offs, wts);
    hipLaunchKernelGGL(k1_axial, dim3(Bn * Cn * 16), dim3(256), 0, stream,
                       x, cnt, offs, wts, t_buf);
    hipLaunchKernelGGL(k2_pw, dim3(Bn * PLANE / 64), dim3(256), 0, stream,
                       t_buf, x, wfuse, bnf_g, bnf_b, bnf_m, bnf_v,
                       dg_wh, dg_ww, dg_g, dg_b, dg_m, dg_v, act_a, out_pre);
    hipLaunchKernelGGL(k3_means, dim3(Bn * Cn), dim3(256), 0, stream,
                       out_pre, xh, xw);
    hipLaunchKernelGGL(k4_att, dim3(Bn), dim3(256), 0, stream,
                       xh, xw, ca_w1, ca_g, ca_b, ca_m, ca_v, ca_a, ca_wh, ca_ww,
                       a_h, a_w);
    hipLaunchKernelGGL(k5_final, dim3(NIMG / 1024), dim3(256), 0, stream,
                       out_pre, a_h, a_w, out);
}

// Round 4
// 320.214 us; speedup vs baseline: 1.5127x; 1.0896x over previous
//
#include <hip/hip_runtime.h>
#include <hip/hip_bf16.h>
#include <math.h>

#define Bn 8
#define Cn 96
#define Hn 128
#define Wn 128
#define PLANE (Hn*Wn)          // 16384
#define NIMG (Bn*Cn*PLANE)     // 12582912
#define EPSV 1e-5f
#define TAPN 48
#define TAPF 8

typedef __attribute__((ext_vector_type(8))) short short8;
typedef __attribute__((ext_vector_type(4))) float floatx4;

union FragU { short8 v; uint2 u2[2]; };

// ---------------------------------------------------------------------------
// K0: merged sparse integer tap lists (zero-padded) + w_fuse -> bf16
// ---------------------------------------------------------------------------
__global__ void k0_taps(
    const float* __restrict__ rm_p, const float* __restrict__ whm, const float* __restrict__ wwm,
    const float* __restrict__ rl_p, const float* __restrict__ whl, const float* __restrict__ wwl,
    const float* __restrict__ w_fuse,
    int* __restrict__ cnt, int* __restrict__ offs, float* __restrict__ wts,
    short* __restrict__ w_bf)
{
    int t = threadIdx.x;              // 0..255
    for (int e = t; e < Cn * Cn; e += 256) {
        __hip_bfloat16 hv = __float2bfloat16(w_fuse[e]);
        w_bf[e] = *(short*)&hv;
    }
    if (t >= Cn * 2) return;
    int c = t >> 1, dir = t & 1;
    for (int k = 0; k < TAPN; ++k) { offs[t * TAPN + k] = 0; wts[t * TAPN + k] = 0.f; }
    const float* tap_m = dir ? (wwm + c * 5) : (whm + c * 5);
    const float* tap_l = dir ? (wwl + c * 5) : (whl + c * 5);
    float rm = fmaxf(rm_p[0], 1.f), rl = fmaxf(rl_p[0], 1.f);
    float dense[TAPN];
    for (int k = 0; k < TAPN; ++k) dense[k] = 0.f;
    for (int pass = 0; pass < 2; ++pass) {
        float r = pass ? rl : rm;
        const float* tp = pass ? tap_l : tap_m;
        for (int i = 0; i < 5; ++i) {
            float s = (float)(i - 2) * r;
            float f = floorf(s);
            float fr = s - f;
            int fi = (int)f + 23;
            if (fi >= 0 && fi < TAPN)         dense[fi]     += tp[i] * (1.f - fr);
            if (fi + 1 >= 0 && fi + 1 < TAPN) dense[fi + 1] += tp[i] * fr;
        }
    }
    int n = 0;
    for (int k = 0; k < TAPN; ++k) {
        if (dense[k] != 0.f) {
            offs[t * TAPN + n] = k - 23;
            wts[t * TAPN + n] = dense[k];
            ++n;
        }
    }
    cnt[t] = n;
}

// ---------------------------------------------------------------------------
// K1: t = 2x + FIR(H) + FIR(W)  (bf16, layout [b][h][c][w])
//     anchor = BN_d(x + dwconv3_h + dwconv3_w)  (fp32, layout [b][c][h][w])
// ---------------------------------------------------------------------------
__global__ __launch_bounds__(256) void k1_axial(
    const float* __restrict__ x,
    const int* __restrict__ cnt, const int* __restrict__ offs, const float* __restrict__ wts,
    const float* __restrict__ dwh, const float* __restrict__ dww,
    const float* __restrict__ dg, const float* __restrict__ db_,
    const float* __restrict__ dm, const float* __restrict__ dv,
    short* __restrict__ t_bf, float* __restrict__ anchor)
{
    __shared__ float pl[8][160];        // 16-col zero pad each side
    __shared__ int   soff[2 * TAPF];
    __shared__ float swt[2 * TAPF];
    __shared__ int   scnt[2];

    int blk = blockIdx.x;               // 768*16
    int bc  = blk >> 4;
    int hg  = blk & 15;
    int b   = bc / Cn;
    int c   = bc % Cn;
    int tid = threadIdx.x;
    int m   = tid & 31;
    int row = tid >> 5;                 // 0..7
    int h   = hg * 8 + row;

    if (tid < 2) scnt[tid] = cnt[c * 2 + tid];
    if (tid < 2 * TAPF) {
        int dir = tid >> 3, j = tid & (TAPF - 1);
        soff[tid] = offs[(c * 2 + dir) * TAPN + j];
        swt[tid]  = wts[(c * 2 + dir) * TAPN + j];
    }
    {
        int pr = tid >> 5, pp = tid & 31;
        pl[pr][pp < 16 ? pp : 128 + pp] = 0.f;
    }
    const float* plane = x + ((long)bc << 14);
    const float* rowp  = plane + (h << 7);
    float v0 = rowp[m], v1 = rowp[m + 32], v2 = rowp[m + 64], v3 = rowp[m + 96];
    pl[row][16 + m]      = v0;
    pl[row][16 + m + 32] = v1;
    pl[row][16 + m + 64] = v2;
    pl[row][16 + m + 96] = v3;
    __syncthreads();

    int cH = scnt[0], cW = scnt[1];
    float a0 = 2.f * v0, a1 = 2.f * v1, a2 = 2.f * v2, a3 = 2.f * v3;

    bool fast = (cH <= TAPF) && (cW <= TAPF);
#pragma unroll
    for (int j = 0; j < TAPF; ++j)
        fast = fast && (soff[TAPF + j] >= -16) && (soff[TAPF + j] <= 16);

    if (fast) {
#pragma unroll
        for (int j = 0; j < TAPF; ++j) {       // H taps (global)
            int y = h + soff[j];
            float wt = (y >= 0 && y < Hn) ? swt[j] : 0.f;
            y = min(max(y, 0), Hn - 1);
            const float* rp = plane + (y << 7);
            a0 += wt * rp[m];
            a1 += wt * rp[m + 32];
            a2 += wt * rp[m + 64];
            a3 += wt * rp[m + 96];
        }
#pragma unroll
        for (int j = 0; j < TAPF; ++j) {       // W taps (LDS, padded)
            int o = soff[TAPF + j];
            float wt = swt[TAPF + j];
            const float* rp = &pl[row][16 + o];
            a0 += wt * rp[m];
            a1 += wt * rp[m + 32];
            a2 += wt * rp[m + 64];
            a3 += wt * rp[m + 96];
        }
    } else {
        const int*   goH = offs + (c * 2 + 0) * TAPN;
        const float* gwH = wts  + (c * 2 + 0) * TAPN;
        const int*   goW = offs + (c * 2 + 1) * TAPN;
        const float* gwW = wts  + (c * 2 + 1) * TAPN;
        for (int j = 0; j < cH; ++j) {
            int y = h + goH[j];
            if (y >= 0 && y < Hn) {
                float wt = gwH[j];
                const float* rp = plane + (y << 7);
                a0 += wt * rp[m];
                a1 += wt * rp[m + 32];
                a2 += wt * rp[m + 64];
                a3 += wt * rp[m + 96];
            }
        }
        for (int j = 0; j < cW; ++j) {
            int o = goW[j];
            float wt = gwW[j];
            const float* rp = plane + (h << 7);
#pragma unroll
            for (int q = 0; q < 4; ++q) {
                int xw = m + 32 * q + o;
                float v = (xw >= 0 && xw < Wn) ? rp[xw] : 0.f;
                float* ap = (q == 0) ? &a0 : (q == 1) ? &a1 : (q == 2) ? &a2 : &a3;
                *ap += wt * v;
            }
        }
    }

    // ----- t (bf16) store, layout [b][h][c][w] -----
    short* tp = t_bf + (((long)(b * Hn + h) * Cn) + c) * Wn;
    {
        __hip_bfloat16 h0 = __float2bfloat16(a0), h1 = __float2bfloat16(a1);
        __hip_bfloat16 h2 = __float2bfloat16(a2), h3 = __float2bfloat16(a3);
        tp[m]      = *(short*)&h0;
        tp[m + 32] = *(short*)&h1;
        tp[m + 64] = *(short*)&h2;
        tp[m + 96] = *(short*)&h3;
    }

    // ----- anchor = BN_d(x + edges) -----
    float e0 = dwh[c * 3], e1 = dwh[c * 3 + 1], e2 = dwh[c * 3 + 2];
    float f0 = dww[c * 3], f1 = dww[c * 3 + 1], f2 = dww[c * 3 + 2];
    float dsc = dg[c] * rsqrtf(dv[c] + EPSV);
    float dof = db_[c] - dm[c] * dsc;
    const float* rup = plane + ((h > 0 ? h - 1 : 0) << 7);
    const float* rdn = plane + ((h < Hn - 1 ? h + 1 : Hn - 1) << 7);
    float u0 = h > 0 ? rup[m] : 0.f, u1 = h > 0 ? rup[m + 32] : 0.f;
    float u2 = h > 0 ? rup[m + 64] : 0.f, u3 = h > 0 ? rup[m + 96] : 0.f;
    float d0 = h < Hn - 1 ? rdn[m] : 0.f, d1 = h < Hn - 1 ? rdn[m + 32] : 0.f;
    float d2 = h < Hn - 1 ? rdn[m + 64] : 0.f, d3 = h < Hn - 1 ? rdn[m + 96] : 0.f;
    float* ap = anchor + ((long)bc << 14) + (h << 7);
#pragma unroll
    for (int q = 0; q < 4; ++q) {
        float vc = (q == 0) ? v0 : (q == 1) ? v1 : (q == 2) ? v2 : v3;
        float vu = (q == 0) ? u0 : (q == 1) ? u1 : (q == 2) ? u2 : u3;
        float vd = (q == 0) ? d0 : (q == 1) ? d1 : (q == 2) ? d2 : d3;
        float vl = pl[row][16 + m + 32 * q - 1];
        float vr = pl[row][16 + m + 32 * q + 1];
        float edges = e0 * vu + e1 * vc + e2 * vd + f0 * vl + f1 * vc + f2 * vr;
        ap[m + 32 * q] = (vc + edges) * dsc + dof;
    }
}

// ---------------------------------------------------------------------------
// K2: out = prelu( BN_f(w @ t) + anchor )  via bf16 MFMA 16x16x32.
// Block = (b, h): 96 outputs x 128 pixels. 4 waves x (6 m-tiles x 2 n-tiles).
// ---------------------------------------------------------------------------
__global__ __launch_bounds__(256) void k2_pw(
    const short* __restrict__ t_bf, const float* __restrict__ anchor,
    const short* __restrict__ w_bf,
    const float* __restrict__ bg, const float* __restrict__ bb,
    const float* __restrict__ bm, const float* __restrict__ bv,
    const float* __restrict__ act_a,
    float* __restrict__ out)
{
    __shared__ short wl[Cn * 100];       // [o][c], stride 100 shorts (200 B)
    __shared__ short tl[Wn * 100];       // [p][c], stride 100 shorts
    __shared__ float sfsc[Cn], sfof[Cn], saa[Cn];

    int tid  = threadIdx.x;
    int blk  = blockIdx.x;               // 1024
    int b    = blk >> 7;
    int h    = blk & 127;
    int lane = tid & 63;
    int wv   = tid >> 6;
    int n16  = lane & 15;
    int quad = lane >> 4;

    // stage w (bf16) -> LDS, u32 writes (c-contiguous)
    {
        const uint* wsrc = (const uint*)w_bf;
        uint* wdst = (uint*)wl;
        for (int e = tid; e < Cn * 48; e += 256) {
            int o = e / 48, cq = e - o * 48;
            wdst[o * 50 + cq] = wsrc[e];
        }
    }
    // BN-fold + prelu params
    if (tid < Cn) {
        float s = bg[tid] * rsqrtf(bv[tid] + EPSV);
        sfsc[tid] = s;
        sfof[tid] = bb[tid] - bm[tid] * s;
        saa[tid]  = act_a[tid];
    }
    // stage t slab [96 c][128 w] -> LDS transposed [p][c] (4-channel packed b64)
    {
        const uint* trow = (const uint*)t_bf + (size_t)(b * Hn + h) * Cn * 64;
#pragma unroll
        for (int rg = 0; rg < 6; ++rg) {
            int c0 = wv * 24 + rg * 4;
            uint v0 = trow[(c0 + 0) * 64 + lane];
            uint v1 = trow[(c0 + 1) * 64 + lane];
            uint v2 = trow[(c0 + 2) * 64 + lane];
            uint v3 = trow[(c0 + 3) * 64 + lane];
            uint2 lo, hi;
            lo.x = (v0 & 0xffffu) | (v1 << 16);
            lo.y = (v2 & 0xffffu) | (v3 << 16);
            hi.x = (v0 >> 16) | (v1 & 0xffff0000u);
            hi.y = (v2 >> 16) | (v3 & 0xffff0000u);
            *(uint2*)(tl + (2 * lane) * 100 + c0)     = lo;
            *(uint2*)(tl + (2 * lane + 1) * 100 + c0) = hi;
        }
    }
    __syncthreads();

    // B fragments for this wave's two n-tiles
    FragU Bf[2][3];
#pragma unroll
    for (int nt = 0; nt < 2; ++nt) {
        int p = (wv * 2 + nt) * 16 + n16;
        const short* bp = tl + p * 100 + quad * 8;
#pragma unroll
        for (int kb = 0; kb < 3; ++kb) {
            Bf[nt][kb].u2[0] = *(const uint2*)(bp + kb * 32);
            Bf[nt][kb].u2[1] = *(const uint2*)(bp + kb * 32 + 4);
        }
    }

    floatx4 acc[6][2];
#pragma unroll
    for (int mt = 0; mt < 6; ++mt)
#pragma unroll
        for (int nt = 0; nt < 2; ++nt)
            acc[mt][nt] = (floatx4){0.f, 0.f, 0.f, 0.f};

#pragma unroll
    for (int mt = 0; mt < 6; ++mt) {
        int o = mt * 16 + n16;
        const short* apg = wl + o * 100 + quad * 8;
        FragU Af[3];
#pragma unroll
        for (int kb = 0; kb < 3; ++kb) {
            Af[kb].u2[0] = *(const uint2*)(apg + kb * 32);
            Af[kb].u2[1] = *(const uint2*)(apg + kb * 32 + 4);
        }
#pragma unroll
        for (int nt = 0; nt < 2; ++nt)
#pragma unroll
            for (int kb = 0; kb < 3; ++kb)
                acc[mt][nt] = __builtin_amdgcn_mfma_f32_16x16x32_bf16(
                    Af[kb].v, Bf[nt][kb].v, acc[mt][nt], 0, 0, 0);
    }

    // epilogue: BN_f + anchor + prelu, coalesced per quad
    long base = (long)b * Cn * PLANE + (h << 7);
#pragma unroll
    for (int mt = 0; mt < 6; ++mt) {
#pragma unroll
        for (int nt = 0; nt < 2; ++nt) {
            int p = (wv * 2 + nt) * 16 + n16;
#pragma unroll
            for (int reg = 0; reg < 4; ++reg) {
                int o = mt * 16 + quad * 4 + reg;
                long idx = base + (long)o * PLANE + p;
                float fused = acc[mt][nt][reg] * sfsc[o] + sfof[o];
                float v = fused + anchor[idx];
                out[idx] = (v >= 0.f) ? v : saa[o] * v;
            }
        }
    }
}

// ---------------------------------------------------------------------------
// K3: per-(b,c) plane: row means -> xh, column means -> xw
// ---------------------------------------------------------------------------
__global__ __launch_bounds__(256) void k3_means(
    const float* __restrict__ op, float* __restrict__ xh, float* __restrict__ xw)
{
    int bc = blockIdx.x;
    const float4* pl = (const float4*)(op + ((long)bc << 14));
    int tid = threadIdx.x;
    int wq = tid & 31;
    int hg = tid >> 5;
    __shared__ float cpart[8][Wn + 4];
    __shared__ float rpart[Hn];
    float4 csum = make_float4(0, 0, 0, 0);
#pragma unroll
    for (int k = 0; k < 16; ++k) {
        int h = hg * 16 + k;
        float4 v = pl[h * 32 + wq];
        csum.x += v.x; csum.y += v.y; csum.z += v.z; csum.w += v.w;
        float rs = v.x + v.y + v.z + v.w;
#pragma unroll
        for (int off = 16; off; off >>= 1) rs += __shfl_down(rs, off, 32);
        if (wq == 0) rpart[h] = rs * (1.f / Wn);
    }
    cpart[hg][wq * 4 + 0] = csum.x;
    cpart[hg][wq * 4 + 1] = csum.y;
    cpart[hg][wq * 4 + 2] = csum.z;
    cpart[hg][wq * 4 + 3] = csum.w;
    __syncthreads();
    if (tid < 128) {
        float s = 0.f;
#pragma unroll
        for (int g = 0; g < 8; ++g) s += cpart[g][tid];
        xw[bc * Wn + tid] = s * (1.f / Hn);
        xh[bc * Hn + tid] = rpart[tid];
    }
}

// ---------------------------------------------------------------------------
// K4: coord-attention MLP
// ---------------------------------------------------------------------------
__global__ __launch_bounds__(256) void k4_att(
    const float* __restrict__ xh, const float* __restrict__ xw,
    const float* __restrict__ w1,
    const float* __restrict__ g, const float* __restrict__ bb,
    const float* __restrict__ m, const float* __restrict__ v,
    const float* __restrict__ aa,
    const float* __restrict__ cwh, const float* __restrict__ cww,
    float* __restrict__ a_h, float* __restrict__ a_w)
{
    int b = blockIdx.x;
    int p = threadIdx.x;
    __shared__ float w1s[8 * Cn];
    __shared__ float whs[Cn * 8];
    __shared__ float wws[Cn * 8];
    for (int e = p; e < 8 * Cn; e += 256) { w1s[e] = w1[e]; whs[e] = cwh[e]; wws[e] = cww[e]; }
    __syncthreads();

    float acc[8];
#pragma unroll
    for (int i = 0; i < 8; ++i) acc[i] = 0.f;
    for (int c = 0; c < Cn; ++c) {
        float yv = (p < Hn) ? xh[(b * Cn + c) * Hn + p] : xw[(b * Cn + c) * Wn + (p - Hn)];
#pragma unroll
        for (int mip = 0; mip < 8; ++mip) acc[mip] += w1s[mip * Cn + c] * yv;
    }
    float y2[8];
#pragma unroll
    for (int mip = 0; mip < 8; ++mip) {
        float sc = g[mip] * rsqrtf(v[mip] + EPSV);
        float t = (acc[mip] - m[mip]) * sc + bb[mip];
        y2[mip] = (t >= 0.f) ? t : aa[mip] * t;
    }
    const float* wsel = (p < Hn) ? whs : wws;
    float* osel = (p < Hn) ? a_h : a_w;
    int pp = (p < Hn) ? p : p - Hn;
    for (int c = 0; c < Cn; ++c) {
        float s = 0.f;
#pragma unroll
        for (int mip = 0; mip < 8; ++mip) s += wsel[c * 8 + mip] * y2[mip];
        osel[(b * Cn + c) * Hn + pp] = 1.f / (1.f + expf(-s));
    }
}

// ---------------------------------------------------------------------------
// K5: out *= a_h[b,c,h] * a_w[b,c,w]   (in-place, float4)
// ---------------------------------------------------------------------------
__global__ __launch_bounds__(256) void k5_final(
    const float* __restrict__ a_h, const float* __restrict__ a_w,
    float* __restrict__ out)
{
    int idx = blockIdx.x * 256 + threadIdx.x;
    int e = idx * 4;
    if (e >= NIMG) return;
    int w = e & 127;
    int h = (e >> 7) & 127;
    int bc = e >> 14;
    float4 vv = *(const float4*)(out + e);
    float ah = a_h[bc * Hn + h];
    float4 aw = *(const float4*)(a_w + bc * Wn + w);
    float4 r;
    r.x = vv.x * ah * aw.x;
    r.y = vv.y * ah * aw.y;
    r.z = vv.z * ah * aw.z;
    r.w = vv.w * ah * aw.w;
    *(float4*)(out + e) = r;
}

// ---------------------------------------------------------------------------
extern "C" void kernel_launch(void* const* d_in, const int* in_sizes, int n_in,
                              void* d_out, int out_size, void* d_ws, size_t ws_size,
                              hipStream_t stream)
{
    const float* x     = (const float*)d_in[0];
    const float* r_m   = (const float*)d_in[1];
    const float* wh_m  = (const float*)d_in[2];
    const float* ww_m  = (const float*)d_in[3];
    const float* r_l   = (const float*)d_in[4];
    const float* wh_l  = (const float*)d_in[5];
    const float* ww_l  = (const float*)d_in[6];
    const float* wfuse = (const float*)d_in[7];
    const float* bnf_g = (const float*)d_in[8];
    const float* bnf_b = (const float*)d_in[9];
    const float* bnf_m = (const float*)d_in[10];
    const float* bnf_v = (const float*)d_in[11];
    const float* dg_wh = (const float*)d_in[12];
    const float* dg_ww = (const float*)d_in[13];
    const float* dg_g  = (const float*)d_in[14];
    const float* dg_b  = (const float*)d_in[15];
    const float* dg_m  = (const float*)d_in[16];
    const float* dg_v  = (const float*)d_in[17];
    const float* act_a = (const float*)d_in[18];
    const float* ca_w1 = (const float*)d_in[19];
    const float* ca_g  = (const float*)d_in[20];
    const float* ca_b  = (const float*)d_in[21];
    const float* ca_m  = (const float*)d_in[22];
    const float* ca_v  = (const float*)d_in[23];
    const float* ca_a  = (const float*)d_in[24];
    const float* ca_wh = (const float*)d_in[25];
    const float* ca_ww = (const float*)d_in[26];

    float* ws     = (float*)d_ws;
    float* anchor = ws;                          // NIMG floats
    float* xh     = anchor + (size_t)NIMG;       // 98304
    float* xw     = xh + Bn * Cn * Hn;
    float* a_h    = xw + Bn * Cn * Wn;
    float* a_w    = a_h + Bn * Cn * Hn;
    float* wts    = a_w + Bn * Cn * Wn;          // 192*48
    int*   cnt    = (int*)(wts + 2 * Cn * TAPN); // 192
    int*   offs   = cnt + 2 * Cn;                // 192*48
    short* t_bf   = (short*)(offs + 2 * Cn * TAPN); // NIMG shorts
    short* w_bf   = t_bf + (size_t)NIMG;         // 9216 shorts

    float* out = (float*)d_out;

    hipLaunchKernelGGL(k0_taps, dim3(1), dim3(256), 0, stream,
                       r_m, wh_m, ww_m, r_l, wh_l, ww_l, wfuse, cnt, offs, wts, w_bf);
    hipLaunchKernelGGL(k1_axial, dim3(Bn * Cn * 16), dim3(256), 0, stream,
                       x, cnt, offs, wts, dg_wh, dg_ww, dg_g, dg_b, dg_m, dg_v,
                       t_bf, anchor);
    hipLaunchKernelGGL(k2_pw, dim3(Bn * Hn), dim3(256), 0, stream,
                       t_bf, anchor, w_bf, bnf_g, bnf_b, bnf_m, bnf_v, act_a, out);
    hipLaunchKernelGGL(k3_means, dim3(Bn * Cn), dim3(256), 0, stream,
                       out, xh, xw);
    hipLaunchKernelGGL(k4_att, dim3(Bn), dim3(256), 0, stream,
                       xh, xw, ca_w1, ca_g, ca_b, ca_m, ca_v, ca_a, ca_wh, ca_ww,
                       a_h, a_w);
    hipLaunchKernelGGL(k5_final, dim3(NIMG / 1024), dim3(256), 0, stream,
                       a_h, a_w, out);
}